// Round 5
// baseline (419.682 us; speedup 1.0000x reference)
//
#include <hip/hip_runtime.h>
#include <hip/hip_bf16.h>
#include <hip/hip_fp16.h>
#include <math.h>

// ---------------------------------------------------------------------------
// ActivityRecognitionGCN: 3x GCNConv(+ReLU) -> mean pool per graph -> MLP head
// N=100000 nodes, E=3.2M edges, G=1024 graphs, F: 128->64->64->32
// R4 -> R5:
//  * partition: EPB 8192->4096 (2x blocks; was 14% occupancy, 1TB/s) and
//    dst staged in LDS (one global read instead of two).
//  * agg: 16B (8-feature) lane loads + 8-deep edge unroll for 2x fewer load
//    instructions and 2x deeper MLP on the random row gathers.
//  * fill: 512 threads per block (histogram/place/streamout 2x faster).
// ---------------------------------------------------------------------------

constexpr int BSHIFT = 8;         // bucket = dst >> 8 (256 nodes per bucket)
constexpr int BMASK  = 255;
constexpr int BCAP   = 10240;     // bucket capacity (mean 8192, +22 sigma)
constexpr int EPB    = 4096;      // edges per partition block

__global__ void zero_int_kernel(int* __restrict__ p, int n) {
  int i = blockIdx.x * blockDim.x + threadIdx.x;
  if (i < n) p[i] = 0;
}

// Partition edges into 256-node buckets. dst staged in LDS; one global pass.
__global__ __launch_bounds__(256) void partition_kernel(const int* __restrict__ src,
    const int* __restrict__ dst, int* __restrict__ bucket_cnt,
    unsigned* __restrict__ part, int E, int nbuckets) {
  __shared__ int lcnt[512];
  __shared__ int lbase[512];
  __shared__ int sdst[EPB];
  const int tid = threadIdx.x;
  const int base = blockIdx.x * EPB;
  const int lim = min(EPB, E - base);
  for (int b = tid; b < nbuckets; b += 256) lcnt[b] = 0;
  __syncthreads();
  for (int j = tid; j < lim; j += 256) {
    int d = dst[base + j];
    sdst[j] = d;
    atomicAdd(&lcnt[d >> BSHIFT], 1);
  }
  __syncthreads();
  for (int b = tid; b < nbuckets; b += 256) {
    lbase[b] = atomicAdd(&bucket_cnt[b], lcnt[b]);
    lcnt[b] = 0;
  }
  __syncthreads();
  for (int j = tid; j < lim; j += 256) {
    int d = sdst[j], s = src[base + j];
    int b = d >> BSHIFT;
    int pos = lbase[b] + atomicAdd(&lcnt[b], 1);
    if (pos < BCAP)
      part[(size_t)b * BCAP + pos] = ((unsigned)(d & BMASK) << 17) | (unsigned)s;
  }
}

// Exclusive scan of bucket_cnt (nb <= 512) in a single block.
__global__ __launch_bounds__(256) void scan_buckets_kernel(const int* __restrict__ cnt,
    int* __restrict__ base, int nb) {
  __shared__ int sh[512];
  const int t = threadIdx.x;
  sh[t] = (t < nb) ? cnt[t] : 0;
  sh[t + 256] = (t + 256 < nb) ? cnt[t + 256] : 0;
  __syncthreads();
  for (int d = 1; d < 512; d <<= 1) {
    int v0 = 0, v1 = 0;
    if (t >= d) v0 = sh[t - d];
    if (t + 256 >= d) v1 = sh[t + 256 - d];
    __syncthreads();
    if (t >= d) sh[t] += v0;
    if (t + 256 >= d) sh[t + 256] += v1;
    __syncthreads();
  }
  if (t < nb) base[t] = (t == 0) ? 0 : sh[t - 1];
  if (t + 256 < nb) base[t + 256] = sh[t + 255];
}

// One block (512 threads) per bucket: LDS degree histogram -> offs/dinv, then
// LDS csr window via local cursors, then coalesced stream-out.
__global__ __launch_bounds__(512) void fill_bucket_kernel(
    const unsigned* __restrict__ part, const int* __restrict__ bucket_cnt,
    const int* __restrict__ bucket_base, int* __restrict__ offs,
    float* __restrict__ dinv, int* __restrict__ csr, int N, int E) {
  __shared__ int lwin[BCAP];
  __shared__ int ldeg[256];
  __shared__ int lscan[512];
  const int b = blockIdx.x;
  const int t = threadIdx.x;
  const int nb0 = b << BSHIFT;
  const int nn = min(1 << BSHIFT, N - nb0);
  const int cnt = min(bucket_cnt[b], BCAP);
  const int wbase = bucket_base[b];
  if (t < 256) ldeg[t] = 0;
  __syncthreads();
  // pass 1: per-node degree histogram
  for (int i = t; i < cnt; i += 512)
    atomicAdd(&ldeg[part[(size_t)b * BCAP + i] >> 17], 1);
  __syncthreads();
  // exclusive scan over 256 node-degrees (uniform barriers, 512 threads)
  const int myv = (t < 256) ? ldeg[t] : 0;
  lscan[t] = myv;
  __syncthreads();
  for (int d = 1; d < 256; d <<= 1) {
    int v = 0;
    if (t >= d && t < 256) v = lscan[t - d];
    __syncthreads();
    if (t >= d && t < 256) lscan[t] += v;
    __syncthreads();
  }
  const int excl = lscan[t] - myv;
  if (t < nn) {
    offs[nb0 + t] = wbase + excl;
    dinv[nb0 + t] = 1.0f / sqrtf((float)(myv + 1));
  }
  if (t == 0 && nb0 + nn == N) offs[N] = E;
  if (t < 256) ldeg[t] = excl;  // becomes local cursor
  __syncthreads();
  // pass 2: place (part segment is L2-hot from pass 1)
  for (int i = t; i < cnt; i += 512) {
    unsigned v = part[(size_t)b * BCAP + i];
    int pos = atomicAdd(&ldeg[v >> 17], 1);
    lwin[pos] = (int)(v & 0x1FFFF);
  }
  __syncthreads();
  // stream out coalesced
  for (int i = t; i < cnt; i += 512) csr[wbase + i] = lwin[i];
}

// ---------------------------------------------------------------------------
// Dense GEMM: Y[N,M](fp16) = X[N,K](fp32) @ W[K,M].  W staged in LDS.
// ---------------------------------------------------------------------------
template <int K, int M>
__global__ __launch_bounds__(256) void gemm_kernel(const float* __restrict__ X,
    const float* __restrict__ W, __half* __restrict__ Y, int n) {
  constexpr int RPB = 32;
  constexpr int XST = K + 4;
  constexpr int MC = M / 16;
  __shared__ __align__(16) float Ws[K * M];
  __shared__ __align__(16) float Xs[RPB * XST];
  const int tid = threadIdx.x;
  const int row0 = blockIdx.x * RPB;
  for (int i = tid * 4; i < K * M; i += 1024)
    *reinterpret_cast<float4*>(&Ws[i]) = *reinterpret_cast<const float4*>(&W[i]);
  for (int i = tid * 4; i < RPB * K; i += 1024) {
    int r = i / K, k = i - r * K;
    int gr = row0 + r;
    float4 v = make_float4(0.f, 0.f, 0.f, 0.f);
    if (gr < n) v = *reinterpret_cast<const float4*>(&X[(size_t)gr * K + k]);
    *reinterpret_cast<float4*>(&Xs[r * XST + k]) = v;
  }
  __syncthreads();
  const int rt = tid & 15;
  const int c = tid >> 4;
  float acc[2][MC];
#pragma unroll
  for (int rr = 0; rr < 2; ++rr)
#pragma unroll
    for (int j = 0; j < MC; ++j) acc[rr][j] = 0.f;
  for (int k4 = 0; k4 < K; k4 += 4) {
    float4 xv[2];
#pragma unroll
    for (int rr = 0; rr < 2; ++rr)
      xv[rr] = *reinterpret_cast<const float4*>(&Xs[(rt + 16 * rr) * XST + k4]);
    const float* xf0 = reinterpret_cast<const float*>(&xv[0]);
    const float* xf1 = reinterpret_cast<const float*>(&xv[1]);
#pragma unroll
    for (int kk = 0; kk < 4; ++kk) {
      float w[MC];
#pragma unroll
      for (int j = 0; j < MC; ++j) w[j] = Ws[(k4 + kk) * M + c * MC + j];
      float x0 = xf0[kk], x1 = xf1[kk];
#pragma unroll
      for (int j = 0; j < MC; ++j) {
        acc[0][j] += x0 * w[j];
        acc[1][j] += x1 * w[j];
      }
    }
  }
#pragma unroll
  for (int rr = 0; rr < 2; ++rr) {
    int gr = row0 + rt + 16 * rr;
    if (gr < n) {
#pragma unroll
      for (int j = 0; j < MC; ++j)
        Y[(size_t)gr * M + c * MC + j] = __float2half(acc[rr][j]);
    }
  }
}

// ---------------------------------------------------------------------------
// Gather-aggregate: F/8 lanes per node, each lane owns 8 features (one 16B
// uint4 load per edge). 8-deep edge unroll for memory-level parallelism.
// ---------------------------------------------------------------------------
__device__ inline void h8_acc(uint4 r, float w, float* acc) {
  const __half2* hp = reinterpret_cast<const __half2*>(&r);
#pragma unroll
  for (int q = 0; q < 4; ++q) {
    float2 f = __half22float2(hp[q]);
    acc[2 * q]     += w * f.x;
    acc[2 * q + 1] += w * f.y;
  }
}

template <int F>
__global__ __launch_bounds__(256) void agg_kernel(const __half* __restrict__ h,
    const int* __restrict__ offs, const int* __restrict__ csr,
    const float* __restrict__ dinv, const float* __restrict__ bias,
    float* __restrict__ out, int n) {
  constexpr int GPN = F / 8;        // lanes per node (8 for F=64, 4 for F=32)
  constexpr int NPB = 256 / GPN;    // nodes per block
  const int node = blockIdx.x * NPB + threadIdx.x / GPN;
  const int fl = (threadIdx.x % GPN) * 8;
  if (node >= n) return;
  const int e0 = offs[node], e1 = offs[node + 1];
  const float di = dinv[node];
  float acc[8];
  {
    uint4 r = *reinterpret_cast<const uint4*>(h + (size_t)node * F + fl);
    const __half2* hp = reinterpret_cast<const __half2*>(&r);
    float w = di * di;
#pragma unroll
    for (int q = 0; q < 4; ++q) {
      float2 f = __half22float2(hp[q]);
      acc[2 * q]     = w * f.x;
      acc[2 * q + 1] = w * f.y;
    }
  }
  int e = e0;
  for (; e + 8 <= e1; e += 8) {
    int sidx[8];
    float wv[8];
    uint4 rv[8];
#pragma unroll
    for (int u = 0; u < 8; ++u) sidx[u] = csr[e + u];
#pragma unroll
    for (int u = 0; u < 8; ++u) wv[u] = di * dinv[sidx[u]];
#pragma unroll
    for (int u = 0; u < 8; ++u)
      rv[u] = *reinterpret_cast<const uint4*>(h + (size_t)sidx[u] * F + fl);
#pragma unroll
    for (int u = 0; u < 8; ++u) h8_acc(rv[u], wv[u], acc);
  }
  for (; e < e1; ++e) {
    int s = csr[e];
    float w = di * dinv[s];
    uint4 r = *reinterpret_cast<const uint4*>(h + (size_t)s * F + fl);
    h8_acc(r, w, acc);
  }
  const float4 b0 = *reinterpret_cast<const float4*>(&bias[fl]);
  const float4 b1 = *reinterpret_cast<const float4*>(&bias[fl + 4]);
  float4 r0 = make_float4(fmaxf(acc[0] + b0.x, 0.f), fmaxf(acc[1] + b0.y, 0.f),
                          fmaxf(acc[2] + b0.z, 0.f), fmaxf(acc[3] + b0.w, 0.f));
  float4 r1 = make_float4(fmaxf(acc[4] + b1.x, 0.f), fmaxf(acc[5] + b1.y, 0.f),
                          fmaxf(acc[6] + b1.z, 0.f), fmaxf(acc[7] + b1.w, 0.f));
  *reinterpret_cast<float4*>(&out[(size_t)node * F + fl]) = r0;
  *reinterpret_cast<float4*>(&out[(size_t)node * F + fl + 4]) = r1;
}

// batch is sorted: per-graph node range via binary search.
__global__ void graph_ranges_kernel(const int* __restrict__ batch, int* __restrict__ gstart,
                                    int n, int G) {
  int g = blockIdx.x * blockDim.x + threadIdx.x;
  if (g > G) return;
  int lo = 0, hi = n;
  while (lo < hi) {
    int mid = (lo + hi) >> 1;
    if (batch[mid] < g) lo = mid + 1; else hi = mid;
  }
  gstart[g] = lo;
}

// One wave per graph: lane = (feature, node parity). Mean over the range.
__global__ __launch_bounds__(256) void pool_kernel(const float* __restrict__ h,
    const int* __restrict__ gstart, float* __restrict__ pooled, int G) {
  int g = blockIdx.x * 4 + (threadIdx.x >> 6);
  if (g >= G) return;
  int lane = threadIdx.x & 63;
  int f = lane & 31, sub = lane >> 5;
  int s = gstart[g], e = gstart[g + 1];
  float acc = 0.f;
  for (int i = s + sub; i < e; i += 2) acc += h[(size_t)i * 32 + f];
  acc += __shfl_xor(acc, 32);
  float mean = acc / fmaxf((float)(e - s), 1.0f);
  if (sub == 0) pooled[g * 32 + f] = mean;
}

// One thread per graph: z = relu(p@Wc1+bc1); logits = z@Wc2+bc2; log_softmax.
__global__ __launch_bounds__(256) void head_kernel(const float* __restrict__ pooled,
    const float* __restrict__ Wc1, const float* __restrict__ bc1,
    const float* __restrict__ Wc2, const float* __restrict__ bc2,
    float* __restrict__ out, int G) {
  int g = blockIdx.x * blockDim.x + threadIdx.x;
  if (g >= G) return;
  float p[32];
#pragma unroll
  for (int k = 0; k < 32; ++k) p[k] = pooled[g * 32 + k];
  float z[16];
#pragma unroll
  for (int j = 0; j < 16; ++j) {
    float a = bc1[j];
#pragma unroll
    for (int k = 0; k < 32; ++k) a += p[k] * Wc1[k * 16 + j];
    z[j] = fmaxf(a, 0.f);
  }
  float lg[16];
  float m = -1e30f;
#pragma unroll
  for (int j = 0; j < 16; ++j) {
    float a = bc2[j];
#pragma unroll
    for (int k = 0; k < 16; ++k) a += z[k] * Wc2[k * 16 + j];
    lg[j] = a;
    m = fmaxf(m, a);
  }
  float ssum = 0.f;
#pragma unroll
  for (int j = 0; j < 16; ++j) ssum += expf(lg[j] - m);
  float lse = logf(ssum);
#pragma unroll
  for (int j = 0; j < 16; ++j) out[g * 16 + j] = lg[j] - m - lse;
}

extern "C" void kernel_launch(void* const* d_in, const int* in_sizes, int n_in,
                              void* d_out, int out_size, void* d_ws, size_t ws_size,
                              hipStream_t stream) {
  const float* x   = (const float*)d_in[0];
  const int*   ei  = (const int*)d_in[1];
  const int*   batch = (const int*)d_in[2];
  const float* W1 = (const float*)d_in[3];
  const float* b1 = (const float*)d_in[4];
  const float* W2 = (const float*)d_in[5];
  const float* b2 = (const float*)d_in[6];
  const float* W3 = (const float*)d_in[7];
  const float* b3 = (const float*)d_in[8];
  const float* Wc1 = (const float*)d_in[9];
  const float* bc1 = (const float*)d_in[10];
  const float* Wc2 = (const float*)d_in[11];
  const float* bc2 = (const float*)d_in[12];

  const int N = in_sizes[2];        // 100000
  const int E = in_sizes[1] / 2;    // 3200000
  const int G = out_size / 16;      // 1024
  const int* src = ei;
  const int* dst = ei + E;
  const int nbuckets = (N + ((1 << BSHIFT) - 1)) >> BSHIFT;  // 391

  char* ws = (char*)d_ws;
  size_t off = 0;
  auto alloc = [&](size_t bytes) -> void* {
    void* p = ws + off;
    off += (bytes + 511) & ~(size_t)511;
    return p;
  };
  int*   offs   = (int*)alloc(((size_t)N + 1) * 4);
  float* dinv   = (float*)alloc((size_t)N * 4);
  int*   gstart = (int*)alloc(((size_t)G + 1) * 4);
  int*   bucket_cnt  = (int*)alloc(2048);
  int*   bucket_base = (int*)alloc(2048);
  int*   csr    = (int*)alloc((size_t)E * 4);
  __half* hbuf  = (__half*)alloc((size_t)N * 64 * 2);   // gemm out (fp16)
  float*  abuf  = (float*)alloc((size_t)N * 64 * 4);    // agg out (fp32)
  float*  pooled = (float*)alloc((size_t)G * 32 * 4);
  // partition scratch (391*10240*4 = 16MB) aliases hbuf(12.8MB)+abuf head:
  // consumed by fill_bucket before gemm1/agg1 overwrite them.
  unsigned* part = (unsigned*)hbuf;
  (void)ws_size; (void)n_in;

  // --- CSR build (reused by all 3 layers) ---
  zero_int_kernel<<<(nbuckets + 255) / 256, 256, 0, stream>>>(bucket_cnt, nbuckets);
  partition_kernel<<<(E + EPB - 1) / EPB, 256, 0, stream>>>(src, dst, bucket_cnt, part,
                                                            E, nbuckets);
  scan_buckets_kernel<<<1, 256, 0, stream>>>(bucket_cnt, bucket_base, nbuckets);
  fill_bucket_kernel<<<nbuckets, 512, 0, stream>>>(part, bucket_cnt, bucket_base,
                                                   offs, dinv, csr, N, E);

  // --- layer 1: 128 -> 64 ---
  gemm_kernel<128, 64><<<(N + 31) / 32, 256, 0, stream>>>(x, W1, hbuf, N);
  agg_kernel<64><<<(N + 31) / 32, 256, 0, stream>>>(hbuf, offs, csr, dinv, b1, abuf, N);
  // --- layer 2: 64 -> 64 ---
  gemm_kernel<64, 64><<<(N + 31) / 32, 256, 0, stream>>>(abuf, W2, hbuf, N);
  agg_kernel<64><<<(N + 31) / 32, 256, 0, stream>>>(hbuf, offs, csr, dinv, b2, abuf, N);
  // --- layer 3: 64 -> 32 ---
  gemm_kernel<64, 32><<<(N + 31) / 32, 256, 0, stream>>>(abuf, W3, hbuf, N);
  agg_kernel<32><<<(N + 63) / 64, 256, 0, stream>>>(hbuf, offs, csr, dinv, b3, abuf, N);

  // --- pool + head ---
  graph_ranges_kernel<<<(G + 256) / 256, 256, 0, stream>>>(batch, gstart, N, G);
  pool_kernel<<<(G + 3) / 4, 256, 0, stream>>>(abuf, gstart, pooled, G);
  head_kernel<<<(G + 255) / 256, 256, 0, stream>>>(pooled, Wc1, bc1, Wc2, bc2,
                                                   (float*)d_out, G);
}